// Round 2
// baseline (112.912 us; speedup 1.0000x reference)
//
#include <hip/hip_runtime.h>

// SplineActivation: out = sum_n Bspline3_n(clip(x,-2,2)) * coeffs[n]
// Uniform knots linspace(-2,2,14), h = 4/13. Closed-form per-interval cubic:
//   i = floor((xc+2)*13/4) in [0,12], t = frac; out = A[i]+B[i]t+G[i]t^2+D[i]t^3
// Special case (reference's .at[-1].add(xc==2)): xc==2 -> coeffs[9].

#define NSPL 10

__global__ __launch_bounds__(256) void spline_act_kernel(
    const float* __restrict__ x,
    const float* __restrict__ coeffs,
    float* __restrict__ out,
    int n4, int n)
{
    // Four separate 16-float arrays: each spans 16 LDS banks -> lanes with
    // distinct interval index hit distinct banks, duplicates broadcast ->
    // conflict-free gather.
    __shared__ float sA[16], sB[16], sG[16], sD[16];

    const int tid = threadIdx.x;
    if (tid < 16) {
        // Padded coeff fetch: c[j] = coeffs[j] if 0<=j<10 else 0
        int j0 = tid - 3, j1 = tid - 2, j2 = tid - 1, j3 = tid;
        float c0 = (j0 >= 0 && j0 < NSPL) ? coeffs[j0] : 0.0f;
        float c1 = (j1 >= 0 && j1 < NSPL) ? coeffs[j1] : 0.0f;
        float c2 = (j2 >= 0 && j2 < NSPL) ? coeffs[j2] : 0.0f;
        float c3 = (j3 >= 0 && j3 < NSPL) ? coeffs[j3] : 0.0f;
        // Uniform cubic B-spline blending, collected by powers of t:
        sA[tid] = (c0 + 4.0f * c1 + c2) * (1.0f / 6.0f);
        sB[tid] = (c2 - c0) * 0.5f;
        sG[tid] = (c0 - 2.0f * c1 + c2) * 0.5f;
        sD[tid] = (c3 - c0 + 3.0f * (c1 - c2)) * (1.0f / 6.0f);
    }
    __syncthreads();

    const float c9 = coeffs[9];  // uniform address -> scalar load

    const int gid = blockIdx.x * blockDim.x + tid;
    const int stride = gridDim.x * blockDim.x;

    const float4* __restrict__ x4 = reinterpret_cast<const float4*>(x);
    float4* __restrict__ o4 = reinterpret_cast<float4*>(out);

    for (int idx = gid; idx < n4; idx += stride) {
        float4 v = x4[idx];
        float4 r;
        float* vi = reinterpret_cast<float*>(&v);
        float* ri = reinterpret_cast<float*>(&r);
#pragma unroll
        for (int k = 0; k < 4; ++k) {
            float xc = fminf(fmaxf(vi[k], -2.0f), 2.0f);
            float s = (xc + 2.0f) * 3.25f;          // * 13/4 (exact)
            int ii = (int)s;
            ii = ii > 12 ? 12 : ii;                  // s==13 only when xc==2
            float t = s - (float)ii;
            float res = fmaf(fmaf(fmaf(sD[ii], t, sG[ii]), t, sB[ii]), t, sA[ii]);
            ri[k] = (xc >= 2.0f) ? c9 : res;
        }
        o4[idx] = r;
    }

    // Scalar tail (n not divisible by 4 — not expected for this shape, but safe)
    for (int idx = n4 * 4 + gid; idx < n; idx += stride) {
        float xc = fminf(fmaxf(x[idx], -2.0f), 2.0f);
        float s = (xc + 2.0f) * 3.25f;
        int ii = (int)s;
        ii = ii > 12 ? 12 : ii;
        float t = s - (float)ii;
        float res = fmaf(fmaf(fmaf(sD[ii], t, sG[ii]), t, sB[ii]), t, sA[ii]);
        out[idx] = (xc >= 2.0f) ? c9 : res;
    }
}

extern "C" void kernel_launch(void* const* d_in, const int* in_sizes, int n_in,
                              void* d_out, int out_size, void* d_ws, size_t ws_size,
                              hipStream_t stream) {
    const float* x = (const float*)d_in[0];
    const float* coeffs = (const float*)d_in[1];
    float* out = (float*)d_out;

    const int n = in_sizes[0];
    const int n4 = n >> 2;

    const int block = 256;
    int grid = (n4 + block - 1) / block;
    if (grid > 2048) grid = 2048;
    if (grid < 1) grid = 1;

    spline_act_kernel<<<grid, block, 0, stream>>>(x, coeffs, out, n4, n);
}